// Round 1
// baseline (474.764 us; speedup 1.0000x reference)
//
#include <hip/hip_runtime.h>
#include <hip/hip_bf16.h>
#include <math.h>

#define B_ 32
#define C_ 256
#define K_ 2048
#define HW_ 784          // 28*28
#define NPIX 25088       // 32*784
#define FEAT_BSTRIDE 230400  // 256*900
#define FEAT_CSTRIDE 900     // 30*30
#define INV_DELTA 15.0f

#define PX 32            // pixels per tile
#define KS 512           // k per slab
#define CC 8             // c chunk
#define EPAD 516         // padded row stride of eT

// ---------------- e2[k] = sum_c emb[k][c]^2 ----------------
__global__ void e2_kernel(const float* __restrict__ emb, float* __restrict__ e2) {
    int t = threadIdx.x;
    int wid = t >> 6, lane = t & 63;
    int k = blockIdx.x * 4 + wid;
    const float* er = emb + (size_t)k * C_;
    float v0 = er[lane], v1 = er[lane + 64], v2 = er[lane + 128], v3 = er[lane + 192];
    float s = v0 * v0 + v1 * v1 + v2 * v2 + v3 * v3;
#pragma unroll
    for (int off = 32; off > 0; off >>= 1) s += __shfl_xor(s, off);
    if (lane == 0) e2[k] = s;
}

// ---------------- B1: GEMM -> raw logits z, per-pixel partial (m,l) ----------------
__global__ __launch_bounds__(256, 2) void gemm_kernel(
    const float* __restrict__ feat, const float* __restrict__ emb,
    const float* __restrict__ mdm, const float* __restrict__ e2,
    float* __restrict__ codes, float* __restrict__ m_part, float* __restrict__ l_part)
{
    __shared__ __align__(16) float fT[C_][PX];   // 32 KB, [c][p]
    __shared__ __align__(16) float eT[CC][EPAD]; // 16.5 KB, [c'][k_local]

    int t = threadIdx.x;
    int tile = blockIdx.x;   // 0..783
    int slab = blockIdx.y;   // 0..3

    // stage f tile: all 256 c for 32 pixels
    {
        int p = t & 31, cg = t >> 5;                 // cg 0..7
        int px = tile * PX + p;
        int b = px / HW_, hw = px % HW_;
        int h = hw / 28, w = hw % 28;
        const float* fb = feat + (size_t)b * FEAT_BSTRIDE + (size_t)(h + 1) * 30 + (w + 1);
#pragma unroll
        for (int i = 0; i < 32; ++i) {
            int c = i * 8 + cg;
            fT[c][p] = fb[(size_t)c * FEAT_CSTRIDE];
        }
    }

    int tp = t >> 6;  // wave id = pixel group (8 px)
    int tk = t & 63;  // k group: k_local = tk*4+j (j<4) and 256+tk*4+(j-4)

    float acc[8][8];
#pragma unroll
    for (int i = 0; i < 8; ++i)
#pragma unroll
        for (int j = 0; j < 8; ++j) acc[i][j] = 0.f;

    const float* eslab = emb + (size_t)slab * KS * C_;

    for (int chunk = 0; chunk < C_ / CC; ++chunk) {
        __syncthreads();
        // stage eT transposed: 512 k x 8 c
        {
            int c4 = (t & 1) * 4;
            int kk0 = t >> 1;  // 0..127
#pragma unroll
            for (int it = 0; it < 4; ++it) {
                int kk = kk0 + it * 128;
                const float4 v = *(const float4*)(eslab + (size_t)kk * C_ + chunk * CC + c4);
                eT[c4 + 0][kk] = v.x; eT[c4 + 1][kk] = v.y;
                eT[c4 + 2][kk] = v.z; eT[c4 + 3][kk] = v.w;
            }
        }
        __syncthreads();
#pragma unroll
        for (int c = 0; c < CC; ++c) {
            float4 e0 = *(const float4*)&eT[c][tk * 4];
            float4 e1 = *(const float4*)&eT[c][256 + tk * 4];
            float4 f0 = *(const float4*)&fT[chunk * CC + c][tp * 8];
            float4 f1 = *(const float4*)&fT[chunk * CC + c][tp * 8 + 4];
            float fv[8] = {f0.x, f0.y, f0.z, f0.w, f1.x, f1.y, f1.z, f1.w};
            float ev[8] = {e0.x, e0.y, e0.z, e0.w, e1.x, e1.y, e1.z, e1.w};
#pragma unroll
            for (int i = 0; i < 8; ++i)
#pragma unroll
                for (int j = 0; j < 8; ++j)
                    acc[i][j] = fmaf(fv[i], ev[j], acc[i][j]);
        }
    }

    // epilogue: z = alpha*(2*dot - e2[k])   (f2 term cancels in softmax)
    float alpha = INV_DELTA / mdm[0];
    int kb = slab * KS + tk * 4;
    float e2v[8];
#pragma unroll
    for (int j = 0; j < 8; ++j) {
        int kg = kb + (j < 4 ? j : 256 + (j - 4));
        e2v[j] = e2[kg];
    }
#pragma unroll
    for (int i = 0; i < 8; ++i)
#pragma unroll
        for (int j = 0; j < 8; ++j)
            acc[i][j] = alpha * (2.f * acc[i][j] - e2v[j]);

    // store raw logits (float4 over contiguous pixels; 8-px runs never straddle b)
    int px0 = tile * PX + tp * 8;
    int b = px0 / HW_, hw0 = px0 % HW_;
    float* cb = codes + (size_t)b * K_ * HW_ + hw0;
#pragma unroll
    for (int j = 0; j < 8; ++j) {
        int kg = kb + (j < 4 ? j : 256 + (j - 4));
        float* cp = cb + (size_t)kg * HW_;
        *(float4*)(cp)     = make_float4(acc[0][j], acc[1][j], acc[2][j], acc[3][j]);
        *(float4*)(cp + 4) = make_float4(acc[4][j], acc[5][j], acc[6][j], acc[7][j]);
    }

    // per-pixel (m,l) over this thread's 8 k, then 64-lane butterfly combine
    float ml[8], ll[8];
#pragma unroll
    for (int i = 0; i < 8; ++i) {
        float m = acc[i][0];
#pragma unroll
        for (int j = 1; j < 8; ++j) m = fmaxf(m, acc[i][j]);
        float l = 0.f;
#pragma unroll
        for (int j = 0; j < 8; ++j) l += __expf(acc[i][j] - m);
        ml[i] = m; ll[i] = l;
    }
#pragma unroll
    for (int off = 1; off < 64; off <<= 1) {
#pragma unroll
        for (int i = 0; i < 8; ++i) {
            float mo = __shfl_xor(ml[i], off);
            float lo = __shfl_xor(ll[i], off);
            float mn = fmaxf(ml[i], mo);
            ll[i] = ll[i] * __expf(ml[i] - mn) + lo * __expf(mo - mn);
            ml[i] = mn;
        }
    }
    if (tk == 0) {
#pragma unroll
        for (int i = 0; i < 8; ++i) {
            m_part[(size_t)slab * NPIX + px0 + i] = ml[i];
            l_part[(size_t)slab * NPIX + px0 + i] = ll[i];
        }
    }
}

// ---------------- combine 4 slab partials -> final m, 1/l ----------------
__global__ void combine_kernel(float* __restrict__ m_part, float* __restrict__ l_part) {
    int p = blockIdx.x * 256 + threadIdx.x;
    if (p >= NPIX) return;
    float m0 = m_part[p],           m1 = m_part[NPIX + p];
    float m2 = m_part[2 * NPIX + p], m3 = m_part[3 * NPIX + p];
    float l0 = l_part[p],           l1 = l_part[NPIX + p];
    float l2 = l_part[2 * NPIX + p], l3 = l_part[3 * NPIX + p];
    float m = fmaxf(fmaxf(m0, m1), fmaxf(m2, m3));
    float l = l0 * __expf(m0 - m) + l1 * __expf(m1 - m) +
              l2 * __expf(m2 - m) + l3 * __expf(m3 - m);
    m_part[p] = m;
    l_part[p] = 1.0f / l;
}

// ---------------- B2: z -> codes (in place), per-(b,k) sums ----------------
#define KT2 32
__global__ __launch_bounds__(256) void softmax_kernel(
    float* __restrict__ codes, const float* __restrict__ m_arr,
    const float* __restrict__ rl_arr, float* __restrict__ bow)
{
    __shared__ __align__(16) float ms[HW_];
    __shared__ __align__(16) float rls[HW_];
    __shared__ float wsum[4][KT2];
    int t = threadIdx.x;
    int b = blockIdx.y, kt = blockIdx.x;
    for (int idx = t; idx < HW_; idx += 256) {
        ms[idx] = m_arr[b * HW_ + idx];
        rls[idx] = rl_arr[b * HW_ + idx];
    }
    __syncthreads();
    int wid = t >> 6, lane = t & 63;
    for (int kk = 0; kk < KT2; ++kk) {
        int k = kt * KT2 + kk;
        float* zp = codes + ((size_t)b * K_ + k) * HW_;
        float s = 0.f;
        if (t < 196) {
            float4 z = *(float4*)(zp + t * 4);
            float4 mv = *(const float4*)&ms[t * 4];
            float4 rv = *(const float4*)&rls[t * 4];
            float c0 = __expf(z.x - mv.x) * rv.x;
            float c1 = __expf(z.y - mv.y) * rv.y;
            float c2 = __expf(z.z - mv.z) * rv.z;
            float c3 = __expf(z.w - mv.w) * rv.w;
            *(float4*)(zp + t * 4) = make_float4(c0, c1, c2, c3);
            s = c0 + c1 + c2 + c3;
        }
#pragma unroll
        for (int off = 32; off > 0; off >>= 1) s += __shfl_xor(s, off);
        if (lane == 0) wsum[wid][kk] = s;
    }
    __syncthreads();
    if (t < KT2) {
        float s = wsum[0][t] + wsum[1][t] + wsum[2][t] + wsum[3][t];
        bow[(size_t)b * K_ + kt * KT2 + t] = s;
    }
}

// ---------------- B3: bow row normalize ----------------
__global__ void bownorm_kernel(float* __restrict__ bow) {
    __shared__ float wred[4];
    __shared__ float denom_s;
    int b = blockIdx.x, t = threadIdx.x;
    float* row = bow + (size_t)b * K_;
    float v[8];
    float s = 0.f;
#pragma unroll
    for (int i = 0; i < 8; ++i) {
        v[i] = row[t + i * 256] * (1.f / 784.f);
        s += fabsf(v[i]);
    }
#pragma unroll
    for (int off = 32; off > 0; off >>= 1) s += __shfl_xor(s, off);
    int wid = t >> 6, lane = t & 63;
    if (lane == 0) wred[wid] = s;
    __syncthreads();
    if (t == 0) denom_s = fmaxf(wred[0] + wred[1] + wred[2] + wred[3], 1e-12f);
    __syncthreads();
    float denom = denom_s;
#pragma unroll
    for (int i = 0; i < 8; ++i) row[t + i * 256] = v[i] / denom;
}

extern "C" void kernel_launch(void* const* d_in, const int* in_sizes, int n_in,
                              void* d_out, int out_size, void* d_ws, size_t ws_size,
                              hipStream_t stream) {
    const float* feat = (const float*)d_in[0];
    const float* emb  = (const float*)d_in[1];
    const float* mdm  = (const float*)d_in[2];
    float* bow   = (float*)d_out;
    float* codes = bow + (size_t)B_ * K_;
    float* ws = (float*)d_ws;
    float* e2 = ws;                       // 2048
    float* m_part = ws + K_;              // 4*25088
    float* l_part = m_part + 4 * NPIX;    // 4*25088   (total ~0.79 MB)

    e2_kernel<<<512, 256, 0, stream>>>(emb, e2);
    gemm_kernel<<<dim3(784, 4), 256, 0, stream>>>(feat, emb, mdm, e2, codes, m_part, l_part);
    combine_kernel<<<98, 256, 0, stream>>>(m_part, l_part);
    softmax_kernel<<<dim3(64, 32), 256, 0, stream>>>(codes, m_part, l_part, bow);
    bownorm_kernel<<<32, 256, 0, stream>>>(bow);
}

// Round 2
// 259.478 us; speedup vs baseline: 1.8297x; 1.8297x over previous
//
#include <hip/hip_runtime.h>
#include <hip/hip_bf16.h>
#include <math.h>

typedef __attribute__((ext_vector_type(8))) short bf16x8;
typedef __attribute__((ext_vector_type(16))) float f32x16;

#define B_ 32
#define C_ 256
#define K_ 2048
#define HW_ 784
#define NPIX 25088
#define FEAT_BSTRIDE 230400
#define FEAT_CSTRIDE 900
#define INV_DELTA 15.0f
#define LOG2E 1.4426950408889634f
#define QSCALE 409.6f
#define QDEC (LOG2E / QSCALE)

#define BM 128
#define BN 128
#define LSTR 40          // ushorts per LDS row: 32 c + 8 pad (80 B, 16B-aligned)
#define NSLAB 16         // 2048 / BN

__device__ __forceinline__ ushort f2bf(float x) {
    __hip_bfloat16 h = __float2bfloat16(x);
    return *reinterpret_cast<ushort*>(&h);
}
__device__ __forceinline__ float bf2f(ushort u) {
    __hip_bfloat16 h;
    *reinterpret_cast<ushort*>(&h) = u;
    return __bfloat162float(h);
}

// ---------------- e2[k] = sum_c emb[k][c]^2 (fp32 exact) ----------------
__global__ void e2_kernel(const float* __restrict__ emb, float* __restrict__ e2) {
    int t = threadIdx.x;
    int wid = t >> 6, lane = t & 63;
    int k = blockIdx.x * 4 + wid;
    const float* er = emb + (size_t)k * C_;
    float v0 = er[lane], v1 = er[lane + 64], v2 = er[lane + 128], v3 = er[lane + 192];
    float s = v0 * v0 + v1 * v1 + v2 * v2 + v3 * v3;
#pragma unroll
    for (int off = 32; off > 0; off >>= 1) s += __shfl_xor(s, off);
    if (lane == 0) e2[k] = s;
}

// ---------------- split embedding into bf16 hi/lo ----------------
__global__ void prep_e_kernel(const float* __restrict__ emb,
                              ushort* __restrict__ ehi, ushort* __restrict__ elo) {
    int i = blockIdx.x * 256 + threadIdx.x;   // 0 .. 524287
    float v = emb[i];
    ushort h = f2bf(v);
    float r = v - bf2f(h);
    ehi[i] = h;
    elo[i] = f2bf(r);
}

// ---------------- MFMA GEMM -> z quantized int16 + per-slab (m,l) ----------------
__global__ __launch_bounds__(256, 2) void gemm_kernel(
    const float* __restrict__ feat, const ushort* __restrict__ ehi,
    const ushort* __restrict__ elo, const float* __restrict__ mdm,
    const float* __restrict__ e2g, ushort* __restrict__ zq,
    float* __restrict__ m_part, float* __restrict__ l_part)
{
    __shared__ ushort Ah[BM * LSTR], Al[BM * LSTR], Bh[BN * LSTR], Bl[BN * LSTR];
    __shared__ float redA[2][132];
    __shared__ float redM[132];

    int t = threadIdx.x;
    int lane = t & 63, wid = t >> 6;          // 4 waves
    int wrow = wid >> 1, wcol = wid & 1;      // 2x2 wave grid, wave tile 64x64
    int g = lane >> 5, ci = lane & 31;

    int px0 = blockIdx.x * BM;
    int k0  = blockIdx.y * BN;

    // fixed pixel per staging thread
    int apx = t & 127;
    int ahalf = t >> 7;
    int pxs = px0 + apx;
    int bs = pxs / HW_, hws = pxs % HW_;
    int hs = hws / 28, wsx = hws % 28;
    const float* fbase = feat + (size_t)bs * FEAT_BSTRIDE + (size_t)(hs + 1) * 30 + (wsx + 1);

    f32x16 acc[2][2];
#pragma unroll
    for (int mi = 0; mi < 2; ++mi)
#pragma unroll
        for (int ni = 0; ni < 2; ++ni)
            acc[mi][ni] = (f32x16)(0.0f);

    for (int kc = 0; kc < 8; ++kc) {
        int c0 = kc * 32;
        __syncthreads();
        // ---- stage A: f fp32 -> bf16 hi/lo, [128 px][32 c] ----
        {
            float v[16];
#pragma unroll
            for (int p = 0; p < 16; ++p)
                v[p] = fbase[(size_t)(c0 + ahalf * 16 + p) * FEAT_CSTRIDE];
#pragma unroll
            for (int o = 0; o < 2; ++o) {
                uint4 uh, ul;
                uint* uhp = reinterpret_cast<uint*>(&uh);
                uint* ulp = reinterpret_cast<uint*>(&ul);
#pragma unroll
                for (int q = 0; q < 4; ++q) {
                    float f0 = v[o * 8 + 2 * q], f1 = v[o * 8 + 2 * q + 1];
                    ushort h0 = f2bf(f0), h1 = f2bf(f1);
                    float r0 = f0 - bf2f(h0), r1 = f1 - bf2f(h1);
                    uhp[q] = (uint)h0 | ((uint)h1 << 16);
                    ulp[q] = (uint)f2bf(r0) | ((uint)f2bf(r1) << 16);
                }
                int oct = ahalf * 2 + o;
                *reinterpret_cast<uint4*>(&Ah[apx * LSTR + oct * 8]) = uh;
                *reinterpret_cast<uint4*>(&Al[apx * LSTR + oct * 8]) = ul;
            }
        }
        // ---- stage B: prepped e hi/lo, [128 k][32 c] ----
        {
#pragma unroll
            for (int i = 0; i < 2; ++i) {
                int idx = t + i * 256;
                int kl = idx >> 2, oct = idx & 3;
                uint4 vh = *reinterpret_cast<const uint4*>(&ehi[(size_t)(k0 + kl) * C_ + c0 + oct * 8]);
                uint4 vl = *reinterpret_cast<const uint4*>(&elo[(size_t)(k0 + kl) * C_ + c0 + oct * 8]);
                *reinterpret_cast<uint4*>(&Bh[kl * LSTR + oct * 8]) = vh;
                *reinterpret_cast<uint4*>(&Bl[kl * LSTR + oct * 8]) = vl;
            }
        }
        __syncthreads();
        // ---- compute: 2 c-steps x (2x2 tiles) x 3 products ----
#pragma unroll
        for (int s = 0; s < 2; ++s) {
            bf16x8 ah[2], av[2], bh[2], bv[2];
#pragma unroll
            for (int mi = 0; mi < 2; ++mi) {
                int off = (wrow * 64 + mi * 32 + ci) * LSTR + s * 16 + g * 8;
                ah[mi] = *reinterpret_cast<const bf16x8*>(&Ah[off]);
                av[mi] = *reinterpret_cast<const bf16x8*>(&Al[off]);
            }
#pragma unroll
            for (int ni = 0; ni < 2; ++ni) {
                int off = (wcol * 64 + ni * 32 + ci) * LSTR + s * 16 + g * 8;
                bh[ni] = *reinterpret_cast<const bf16x8*>(&Bh[off]);
                bv[ni] = *reinterpret_cast<const bf16x8*>(&Bl[off]);
            }
#pragma unroll
            for (int mi = 0; mi < 2; ++mi)
#pragma unroll
                for (int ni = 0; ni < 2; ++ni) {
                    acc[mi][ni] = __builtin_amdgcn_mfma_f32_32x32x16_bf16(ah[mi], bh[ni], acc[mi][ni], 0, 0, 0);
                    acc[mi][ni] = __builtin_amdgcn_mfma_f32_32x32x16_bf16(ah[mi], bv[ni], acc[mi][ni], 0, 0, 0);
                    acc[mi][ni] = __builtin_amdgcn_mfma_f32_32x32x16_bf16(av[mi], bh[ni], acc[mi][ni], 0, 0, 0);
                }
        }
    }

    // ---------------- epilogue ----------------
    const float alpha = INV_DELTA / mdm[0];
    float e2v[2];
#pragma unroll
    for (int ni = 0; ni < 2; ++ni) e2v[ni] = e2g[k0 + wcol * 64 + ni * 32 + ci];
#pragma unroll
    for (int mi = 0; mi < 2; ++mi)
#pragma unroll
        for (int ni = 0; ni < 2; ++ni)
            acc[mi][ni] = alpha * (2.0f * acc[mi][ni] - e2v[ni]);

    // per-pixel max over this wave's 64 cols
    float ms[2][16];
    {
        float mt[2][16];
#pragma unroll
        for (int mi = 0; mi < 2; ++mi)
#pragma unroll
            for (int r = 0; r < 16; ++r)
                mt[mi][r] = fmaxf(acc[mi][0][r], acc[mi][1][r]);
#pragma unroll
        for (int off = 1; off < 32; off <<= 1)
#pragma unroll
            for (int mi = 0; mi < 2; ++mi)
#pragma unroll
                for (int r = 0; r < 16; ++r)
                    mt[mi][r] = fmaxf(mt[mi][r], __shfl_xor(mt[mi][r], off));
        if (ci == 0) {
#pragma unroll
            for (int mi = 0; mi < 2; ++mi)
#pragma unroll
                for (int r = 0; r < 16; ++r)
                    redA[wcol][wrow * 64 + mi * 32 + (r & 3) + 8 * (r >> 2) + 4 * g] = mt[mi][r];
        }
    }
    __syncthreads();
    if (t < 128) redM[t] = fmaxf(redA[0][t], redA[1][t]);
    __syncthreads();
#pragma unroll
    for (int mi = 0; mi < 2; ++mi)
#pragma unroll
        for (int r = 0; r < 16; ++r)
            ms[mi][r] = redM[wrow * 64 + mi * 32 + (r & 3) + 8 * (r >> 2) + 4 * g];

    // per-pixel sum of exp over this wave's cols
    {
        float lt[2][16];
#pragma unroll
        for (int mi = 0; mi < 2; ++mi)
#pragma unroll
            for (int r = 0; r < 16; ++r)
                lt[mi][r] = exp2f((acc[mi][0][r] - ms[mi][r]) * LOG2E) +
                            exp2f((acc[mi][1][r] - ms[mi][r]) * LOG2E);
#pragma unroll
        for (int off = 1; off < 32; off <<= 1)
#pragma unroll
            for (int mi = 0; mi < 2; ++mi)
#pragma unroll
                for (int r = 0; r < 16; ++r)
                    lt[mi][r] += __shfl_xor(lt[mi][r], off);
        if (ci == 0) {
#pragma unroll
            for (int mi = 0; mi < 2; ++mi)
#pragma unroll
                for (int r = 0; r < 16; ++r)
                    redA[wcol][wrow * 64 + mi * 32 + (r & 3) + 8 * (r >> 2) + 4 * g] = lt[mi][r];
        }
    }
    __syncthreads();
    if (t < 128) {
        int slab = blockIdx.y;
        m_part[(size_t)slab * NPIX + px0 + t] = redM[t];
        l_part[(size_t)slab * NPIX + px0 + t] = redA[0][t] + redA[1][t];
    }

    // quantized z store: q = (z - m_slab) * 409.6 as int16, [b][k][hw]
#pragma unroll
    for (int mi = 0; mi < 2; ++mi)
#pragma unroll
        for (int ni = 0; ni < 2; ++ni) {
            int k = k0 + wcol * 64 + ni * 32 + ci;
#pragma unroll
            for (int r = 0; r < 16; r += 2) {
                int row = wrow * 64 + mi * 32 + (r & 3) + 8 * (r >> 2) + 4 * g;
                int pxx = px0 + row;
                int bb = pxx / HW_, hh = pxx - bb * HW_;
                float s0 = fmaxf((acc[mi][ni][r]     - ms[mi][r])     * QSCALE, -32760.f);
                float s1 = fmaxf((acc[mi][ni][r + 1] - ms[mi][r + 1]) * QSCALE, -32760.f);
                int q0 = (int)s0, q1 = (int)s1;
                uint u = ((uint)(ushort)(short)q0) | (((uint)(ushort)(short)q1) << 16);
                *reinterpret_cast<uint*>(&zq[(size_t)(bb * K_ + k) * HW_ + hh]) = u;
            }
        }
}

// ---------------- combine 16 slab partials ----------------
__global__ void combine_kernel(const float* __restrict__ m_part, const float* __restrict__ l_part,
                               float* __restrict__ m_fin, float* __restrict__ rl_g) {
    int p = blockIdx.x * 256 + threadIdx.x;
    float m = -3.4e38f;
#pragma unroll
    for (int s = 0; s < NSLAB; ++s) m = fmaxf(m, m_part[(size_t)s * NPIX + p]);
    float l = 0.f;
#pragma unroll
    for (int s = 0; s < NSLAB; ++s)
        l += l_part[(size_t)s * NPIX + p] * exp2f((m_part[(size_t)s * NPIX + p] - m) * LOG2E);
    m_fin[p] = m;
    rl_g[p] = 1.0f / l;
}

// ---------------- finish: decode zq -> codes + bow ----------------
__global__ __launch_bounds__(256) void finish_kernel(
    const ushort* __restrict__ zq, const float* __restrict__ m_part,
    const float* __restrict__ m_fin, const float* __restrict__ rl_g,
    float* __restrict__ codes, float* __restrict__ bow)
{
    __shared__ float corr[HW_], rls[HW_];
    __shared__ float bsum[64][4];
    int t = threadIdx.x;
    int kc = blockIdx.x, b = blockIdx.y;
    int slab = kc >> 1;
    for (int i = t; i < HW_; i += 256) {
        int p = b * HW_ + i;
        corr[i] = (m_part[(size_t)slab * NPIX + p] - m_fin[p]) * LOG2E;
        rls[i] = rl_g[p];
    }
    __syncthreads();
    int wid = t >> 6, lane = t & 63;
    for (int kl = 0; kl < 64; ++kl) {
        int k = kc * 64 + kl;
        size_t base = ((size_t)b * K_ + k) * HW_;
        float ssum = 0.f;
        if (t < 196) {
            uint2 raw = *reinterpret_cast<const uint2*>(&zq[base + t * 4]);
            int q0 = (int)(short)(raw.x & 0xffffu), q1 = (int)(short)(raw.x >> 16);
            int q2 = (int)(short)(raw.y & 0xffffu), q3 = (int)(short)(raw.y >> 16);
            float4 out;
            out.x = exp2f(fmaf((float)q0, QDEC, corr[t * 4 + 0])) * rls[t * 4 + 0];
            out.y = exp2f(fmaf((float)q1, QDEC, corr[t * 4 + 1])) * rls[t * 4 + 1];
            out.z = exp2f(fmaf((float)q2, QDEC, corr[t * 4 + 2])) * rls[t * 4 + 2];
            out.w = exp2f(fmaf((float)q3, QDEC, corr[t * 4 + 3])) * rls[t * 4 + 3];
            *reinterpret_cast<float4*>(&codes[base + t * 4]) = out;
            ssum = out.x + out.y + out.z + out.w;
        }
#pragma unroll
        for (int off = 32; off > 0; off >>= 1) ssum += __shfl_xor(ssum, off);
        if (lane == 0) bsum[kl][wid] = ssum;
    }
    __syncthreads();
    if (t < 64) {
        float s = bsum[t][0] + bsum[t][1] + bsum[t][2] + bsum[t][3];
        bow[(size_t)b * K_ + kc * 64 + t] = s * (1.0f / 784.0f);
    }
}

// ---------------- bow row normalize ----------------
__global__ void bownorm_kernel(float* __restrict__ bow) {
    __shared__ float wred[4];
    __shared__ float denom_s;
    int b = blockIdx.x, t = threadIdx.x;
    float* row = bow + (size_t)b * K_;
    float v[8];
    float s = 0.f;
#pragma unroll
    for (int i = 0; i < 8; ++i) {
        v[i] = row[t + i * 256];
        s += fabsf(v[i]);
    }
#pragma unroll
    for (int off = 32; off > 0; off >>= 1) s += __shfl_xor(s, off);
    int wid = t >> 6, lane = t & 63;
    if (lane == 0) wred[wid] = s;
    __syncthreads();
    if (t == 0) denom_s = fmaxf(wred[0] + wred[1] + wred[2] + wred[3], 1e-12f);
    __syncthreads();
    float denom = denom_s;
#pragma unroll
    for (int i = 0; i < 8; ++i) row[t + i * 256] = v[i] / denom;
}

extern "C" void kernel_launch(void* const* d_in, const int* in_sizes, int n_in,
                              void* d_out, int out_size, void* d_ws, size_t ws_size,
                              hipStream_t stream) {
    const float* feat = (const float*)d_in[0];
    const float* emb  = (const float*)d_in[1];
    const float* mdm  = (const float*)d_in[2];
    float* bow   = (float*)d_out;
    float* codes = bow + (size_t)B_ * K_;

    char* ws = (char*)d_ws;
    size_t off = 0;
    auto alloc = [&](size_t bytes) { char* p = ws + off; off = (off + bytes + 255) & ~(size_t)255; return p; };
    ushort* ehi   = (ushort*)alloc((size_t)K_ * C_ * 2);
    ushort* elo   = (ushort*)alloc((size_t)K_ * C_ * 2);
    float*  e2    = (float*)alloc(K_ * 4);
    float*  m_part = (float*)alloc((size_t)NSLAB * NPIX * 4);
    float*  l_part = (float*)alloc((size_t)NSLAB * NPIX * 4);
    float*  m_fin = (float*)alloc((size_t)NPIX * 4);
    float*  rl_g  = (float*)alloc((size_t)NPIX * 4);
    ushort* zq    = (ushort*)alloc((size_t)NPIX * K_ * 2);

    e2_kernel<<<512, 256, 0, stream>>>(emb, e2);
    prep_e_kernel<<<2048, 256, 0, stream>>>(emb, ehi, elo);
    gemm_kernel<<<dim3(196, 16), 256, 0, stream>>>(feat, ehi, elo, mdm, e2, zq, m_part, l_part);
    combine_kernel<<<98, 256, 0, stream>>>(m_part, l_part, m_fin, rl_g);
    finish_kernel<<<dim3(32, 32), 256, 0, stream>>>(zq, m_part, m_fin, rl_g, codes, bow);
    bownorm_kernel<<<32, 256, 0, stream>>>(bow);
}